// Round 9
// baseline (98.636 us; speedup 1.0000x reference)
//
#include <hip/hip_runtime.h>
#include <hip/hip_bf16.h>
#include <math.h>

#define LEN_M   131328
#define D_P1    513
#define NROW    4096
#define PRED_ELEMS (NROW * 64)            // 262144

// ws: wcbt bf16, 512 KB: 8 k-chunks (kc) of 64 KB; each is the LDS image
// [512 c][64 k] with 16B-chunk swizzle g' = g ^ (c&7)  (g = k/8 within kc).
// chunk_idx(c, g, kc) = kc*4096 + c*8 + (g ^ (c&7))
typedef __attribute__((ext_vector_type(8))) short short8;     // 8 bf16 = 4 VGPR
typedef __attribute__((ext_vector_type(4))) float floatx4;    // mfma acc
typedef __attribute__((ext_vector_type(2))) float v2f;        // packed fp32

__device__ __forceinline__ void gl_lds16(const void* g, void* l)
{
    __builtin_amdgcn_global_load_lds(
        (const __attribute__((address_space(1))) unsigned int*)g,
        (__attribute__((address_space(3))) unsigned int*)l, 16, 0, 0);
}

__device__ __forceinline__ unsigned short bf16b(float f)
{
    __hip_bfloat16 h = __float2bfloat16(f);
    return *(unsigned short*)&h;
}

// ------------------------------------------------------------------ prep ----
// blocks [0,513): m_w0 / v_w0 outputs (513*256 == LEN_M exactly)
// blocks [513,577): build swizzled wcbt via LDS transpose
__global__ __launch_bounds__(256) void prep_kernel(
    const float* __restrict__ params, float* __restrict__ out,
    __hip_bfloat16* __restrict__ wcbt)
{
    __shared__ unsigned short T[64][65];
    const int bid = blockIdx.x;
    const int t   = threadIdx.x;

    if (bid < 513) {
        int i = bid * 256 + t;
        float m = params[i];
        float v = fmaxf(params[LEN_M + i], 0.0f) + 1e-6f;
        out[PRED_ELEMS + i]         = m;                 // m_w0
        out[PRED_ELEMS + LEN_M + i] = v;                 // v_w0
        return;
    }

    const int b2 = bid - 513;
    const int k0 = (b2 & 7) * 64;
    const int c0 = (b2 >> 3) * 64;
    const int hh = t & 63, kb = t >> 6;
    const bool spart = (c0 >= 256);
    const int hbase = c0 & 255;
    const float* src = params + (spart ? LEN_M : 0);

    #pragma unroll 4
    for (int p = 0; p < 16; ++p) {
        int kk = p * 4 + kb;
        float v = src[(k0 + kk) * 256 + hbase + hh];
        if (spart) v = sqrtf(fmaxf(v, 0.0f) + 1e-6f);
        T[kk][hh] = bf16b(v);
    }
    __syncthreads();

    const int cc = t >> 2, kq = t & 3;
    short8 lo, hi;
    #pragma unroll
    for (int j = 0; j < 8; ++j) lo[j] = (short)T[kq * 16 + j][cc];
    #pragma unroll
    for (int j = 0; j < 8; ++j) hi[j] = (short)T[kq * 16 + 8 + j][cc];

    const int cR = c0 + cc;
    const int g1 = (k0 >> 3) + 2 * kq;                   // global k-chunk 0..63
    const int g2 = g1 + 1;
    const int d1 = (g1 >> 3) * 4096 + cR * 8 + ((g1 & 7) ^ (cR & 7));
    const int d2 = (g2 >> 3) * 4096 + cR * 8 + ((g2 & 7) ^ (cR & 7));
    short* wb = (short*)wcbt;
    *(short8*)(wb + d1 * 8) = lo;
    *(short8*)(wb + d2 * 8) = hi;
}

// ------------------------------------------------------------------ main ----
// 256 blocks x 512 threads (8 waves). Block owns rows [bm, bm+16) x ALL 512
// cols. B streamed in 8 chunks of [512 c][64 k] (64 KB), double-buffered,
// identity global_load_lds from pre-swizzled wcbt. A panel 16x512 in LDS.
// No atomics: pred rows exclusively owned, direct stores -> IDEMPOTENT
// (this round it is launched twice as a duration probe).
// Dynamic LDS: B0 @0 (64K), B1 @64K, A @128K (16K) = 144 KB. 1 block/CU.
__global__ __launch_bounds__(512) void main_kernel(
    const __hip_bfloat16* __restrict__ wcbt, const float* __restrict__ params,
    const float* __restrict__ x, const float* __restrict__ W1,
    const float* __restrict__ eps, float* __restrict__ out)
{
    extern __shared__ char smem[];
    char*  Ap = smem + 131072;                           // [16 r][512 k] bf16
    float* Cl = (float*)smem;                            // [512 c][20] (alias B0)
    float* P  = (float*)(smem + 40960);                  // partial 4 KB

    const int t = threadIdx.x;
    const int w = t >> 6, lane = t & 63;
    const int lane15 = lane & 15, quad = lane >> 4;
    const int ax7 = lane15 & 7;
    const int bm = blockIdx.x * 16;

    const char* wbase = (const char*)wcbt;

    // ---- issue B chunk 0 staging (8 x 16B per thread, identity copy)
    #pragma unroll
    for (int i = 0; i < 8; ++i)
        gl_lds16(wbase + (0 * 4096 + i * 512 + t) * 16, smem + i * 8192 + t * 16);

    // ---- A panel staging: thread -> (row t>>5, k-range (t&31)*16..+16)
    {
        const int r = t >> 5, seg = t & 31;
        const float* xrow = x + (bm + r) * D_P1 + seg * 16;
        #pragma unroll
        for (int c2 = 0; c2 < 2; ++c2) {
            int g  = seg * 2 + c2;
            int cs = (g & ~7) | ((g & 7) ^ (r & 7));
            short8 pk;
            #pragma unroll
            for (int j = 0; j < 8; ++j) pk[j] = (short)bf16b(xrow[c2 * 8 + j]);
            *(short8*)(Ap + r * 1024 + cs * 16) = pk;
        }
    }

    // ---- early independent loads (k=512 fixup, eps, wl)
    const float e = eps[lane];
    float xl[4];
    #pragma unroll
    for (int i = 0; i < 4; ++i)
        xl[i] = x[(bm + quad * 4 + i) * D_P1 + 512];
    float wl[4];
    #pragma unroll
    for (int s = 0; s < 4; ++s) {
        int c = (s < 2 ? 0 : 256) + w * 32 + (s & 1) * 16 + lane15;
        wl[s] = (c < 256) ? params[131072 + c]
                          : sqrtf(fmaxf(params[LEN_M + 131072 + (c - 256)], 0.0f) + 1e-6f);
    }

    // ---- fragment column byte-bases (c&7 == lane15&7 for all four)
    int cb[4];
    #pragma unroll
    for (int s = 0; s < 4; ++s)
        cb[s] = ((s < 2 ? 0 : 256) + w * 32 + (s & 1) * 16 + lane15) * 128;

    floatx4 acc[4];
    #pragma unroll
    for (int s = 0; s < 4; ++s) acc[s] = (floatx4){0.f, 0.f, 0.f, 0.f};

    __syncthreads();                                     // A + B chunk 0 ready

    for (int kc = 0; kc < 8; ++kc) {
        // prefetch next chunk into the other buffer
        if (kc < 7) {
            const int nb = (kc + 1) & 1;
            #pragma unroll
            for (int i = 0; i < 8; ++i)
                gl_lds16(wbase + ((kc + 1) * 4096 + i * 512 + t) * 16,
                         smem + nb * 65536 + i * 8192 + t * 16);
        }
        const char* Bb = smem + (kc & 1) * 65536;
        const char* Ab = Ap + lane15 * 1024 + kc * 128;
        #pragma unroll
        for (int kk = 0; kk < 2; ++kk) {
            const int off = ((kk * 4 + quad) ^ ax7) * 16;
            short8 a  = *(const short8*)(Ab + off);
            short8 b0 = *(const short8*)(Bb + cb[0] + off);
            short8 b1 = *(const short8*)(Bb + cb[1] + off);
            short8 b2 = *(const short8*)(Bb + cb[2] + off);
            short8 b3 = *(const short8*)(Bb + cb[3] + off);
            acc[0] = __builtin_amdgcn_mfma_f32_16x16x32_bf16(a, b0, acc[0], 0, 0, 0);
            acc[1] = __builtin_amdgcn_mfma_f32_16x16x32_bf16(a, b1, acc[1], 0, 0, 0);
            acc[2] = __builtin_amdgcn_mfma_f32_16x16x32_bf16(a, b2, acc[2], 0, 0, 0);
            acc[3] = __builtin_amdgcn_mfma_f32_16x16x32_bf16(a, b3, acc[3], 0, 0, 0);
        }
        __syncthreads();                                 // prefetch drained, buf safe
    }

    // ---- fixup k=512 + C -> LDS [c][20] (aliases B0; all B reads done)
    #pragma unroll
    for (int s = 0; s < 4; ++s) {
        int gc = (s < 2 ? 0 : 256) + w * 32 + (s & 1) * 16 + lane15;
        float4 o;
        o.x = acc[s][0] + xl[0] * wl[s];
        o.y = acc[s][1] + xl[1] * wl[s];
        o.z = acc[s][2] + xl[2] * wl[s];
        o.w = acc[s][3] + xl[3] * wl[s];
        *(float4*)&Cl[gc * 20 + quad * 4] = o;
    }
    __syncthreads();

    // ---- pred epilogue: lane = m; wave w: rows (w&3)*4..+4, h-half (w>>2)
    const int rq = (w & 3) * 4;
    const int hb = (w >> 2) * 128;
    v2f a01s = {0.f, 0.f}, a23s = {0.f, 0.f};
    const v2f e2 = {e, e}, z2 = {0.f, 0.f};

    #pragma unroll 4
    for (int hh = 0; hh < 128; ++hh) {
        const int h = hb + hh;
        const float w1h = W1[1 + h];
        const v2f w2 = {w1h, w1h};
        const float4 av = *(const float4*)&Cl[h * 20 + rq];
        const float4 bv = *(const float4*)&Cl[(256 + h) * 20 + rq];
        v2f a01 = {av.x, av.y}, a23 = {av.z, av.w};
        v2f b01 = {bv.x, bv.y}, b23 = {bv.z, bv.w};
        v2f t01 = __builtin_elementwise_max(__builtin_elementwise_fma(e2, b01, a01), z2);
        v2f t23 = __builtin_elementwise_max(__builtin_elementwise_fma(e2, b23, a23), z2);
        a01s = __builtin_elementwise_fma(t01, w2, a01s);
        a23s = __builtin_elementwise_fma(t23, w2, a23s);
    }

    // ---- combine h-halves (waves 4-7 -> LDS, waves 0-3 add + store)
    if (w >= 4) {
        float* p = P + (w - 4) * 256 + lane;
        p[0]   = a01s.x; p[64]  = a01s.y;
        p[128] = a23s.x; p[192] = a23s.y;
    }
    __syncthreads();
    if (w < 4) {
        const float b0 = W1[0];
        const float* p = P + w * 256 + lane;
        float* op = out + (bm + rq) * 64 + lane;
        op[0]   = a01s.x + p[0]   + b0;
        op[64]  = a01s.y + p[64]  + b0;
        op[128] = a23s.x + p[128] + b0;
        op[192] = a23s.y + p[192] + b0;
    }
}

// -------------------------------------------------------------- launch ------
extern "C" void kernel_launch(void* const* d_in, const int* in_sizes, int n_in,
                              void* d_out, int out_size, void* d_ws, size_t ws_size,
                              hipStream_t stream)
{
    const float* params = (const float*)d_in[0];
    const float* W1     = (const float*)d_in[1];
    const float* x      = (const float*)d_in[2];
    const float* eps    = (const float*)d_in[3];
    float* out = (float*)d_out;
    __hip_bfloat16* wcbt = (__hip_bfloat16*)d_ws;

    static bool attr_set = false;
    if (!attr_set) {
        hipFuncSetAttribute((const void*)main_kernel,
                            hipFuncAttributeMaxDynamicSharedMemorySize, 147456);
        attr_set = true;
    }

    prep_kernel<<<513 + 64, 256, 0, stream>>>(params, out, wcbt);
    // PROBE: main is idempotent (direct stores) — launch twice; the dur_us
    // delta vs R8 measures main's true per-dispatch cost (+1 gap).
    main_kernel<<<256, 512, 147456, stream>>>(wcbt, params, x, W1, eps, out);
    main_kernel<<<256, 512, 147456, stream>>>(wcbt, params, x, W1, eps, out);
}

// Round 10
// 84.525 us; speedup vs baseline: 1.1669x; 1.1669x over previous
//
#include <hip/hip_runtime.h>
#include <hip/hip_bf16.h>
#include <math.h>

#define LEN_M   131328
#define D_P1    513
#define NROW    4096
#define PRED_ELEMS (NROW * 64)            // 262144

// ws: wcbt bf16, 512 KB: 8 k-chunks (kc) of 64 KB; each is the image
// [512 c][64 k] with 16B-chunk swizzle g' = g ^ (c&7)  (g = k-chunk 0..7).
// chunk_idx(c, g, kc) = kc*4096 + c*8 + (g ^ (c&7))
typedef __attribute__((ext_vector_type(8))) short short8;     // 8 bf16 = 4 VGPR
typedef __attribute__((ext_vector_type(4))) float floatx4;    // mfma acc
typedef __attribute__((ext_vector_type(2))) float v2f;        // packed fp32

__device__ __forceinline__ void gl_lds16(const void* g, void* l)
{
    __builtin_amdgcn_global_load_lds(
        (const __attribute__((address_space(1))) unsigned int*)g,
        (__attribute__((address_space(3))) unsigned int*)l, 16, 0, 0);
}

__device__ __forceinline__ unsigned short bf16b(float f)
{
    __hip_bfloat16 h = __float2bfloat16(f);
    return *(unsigned short*)&h;
}

// ------------------------------------------------------------------ prep ----
// blocks [0,513): m_w0 / v_w0 outputs (513*256 == LEN_M exactly)
// blocks [513,769): zero pred region (atomic accumulation base)
// blocks [769,833): build swizzled wcbt via LDS transpose
__global__ __launch_bounds__(256) void prep_kernel(
    const float* __restrict__ params, float* __restrict__ out,
    __hip_bfloat16* __restrict__ wcbt)
{
    __shared__ unsigned short T[64][65];
    const int bid = blockIdx.x;
    const int t   = threadIdx.x;

    if (bid < 513) {
        int i = bid * 256 + t;
        float m = params[i];
        float v = fmaxf(params[LEN_M + i], 0.0f) + 1e-6f;
        out[PRED_ELEMS + i]         = m;                 // m_w0
        out[PRED_ELEMS + LEN_M + i] = v;                 // v_w0
        return;
    }
    if (bid < 769) {
        int i = (bid - 513) * 1024 + t * 4;
        float4 z = {0.f, 0.f, 0.f, 0.f};
        *(float4*)(out + i) = z;
        return;
    }

    const int b2 = bid - 769;
    const int k0 = (b2 & 7) * 64;
    const int c0 = (b2 >> 3) * 64;
    const int hh = t & 63, kb = t >> 6;
    const bool spart = (c0 >= 256);
    const int hbase = c0 & 255;
    const float* src = params + (spart ? LEN_M : 0);

    #pragma unroll 4
    for (int p = 0; p < 16; ++p) {
        int kk = p * 4 + kb;
        float v = src[(k0 + kk) * 256 + hbase + hh];
        if (spart) v = sqrtf(fmaxf(v, 0.0f) + 1e-6f);
        T[kk][hh] = bf16b(v);
    }
    __syncthreads();

    const int cc = t >> 2, kq = t & 3;
    short8 lo, hi;
    #pragma unroll
    for (int j = 0; j < 8; ++j) lo[j] = (short)T[kq * 16 + j][cc];
    #pragma unroll
    for (int j = 0; j < 8; ++j) hi[j] = (short)T[kq * 16 + 8 + j][cc];

    const int cR = c0 + cc;
    const int g1 = (k0 >> 3) + 2 * kq;                   // global 16B-chunk 0..63
    const int g2 = g1 + 1;
    const int d1 = (g1 >> 3) * 4096 + cR * 8 + ((g1 & 7) ^ (cR & 7));
    const int d2 = (g2 >> 3) * 4096 + cR * 8 + ((g2 & 7) ^ (cR & 7));
    short* wb = (short*)wcbt;
    *(short8*)(wb + d1 * 8) = lo;
    *(short8*)(wb + d2 * 8) = hi;
}

// ------------------------------------------------------------------ main ----
// 512 blocks x 512 threads. Block (r = bid>>1, half = bid&1) owns rows
// [r*16, r*16+16) x 256 cols: m-cols h in [half*128,+128) AND s-cols same h
// (relu pairing stays block-local). B streamed in 8 chunks of [256 c][64 k]
// (32 KB) double-buffered. LDS = 2*32K (B) + 16K (A) = 80 KB -> 2 blocks/CU:
// one block's L2-bound B-stream overlaps the other's VALU-bound epilogue.
// Pred combined across h-halves via unsafeAtomicAdd (out pre-zeroed).
__global__ __launch_bounds__(512) void main_kernel(
    const __hip_bfloat16* __restrict__ wcbt, const float* __restrict__ params,
    const float* __restrict__ x, const float* __restrict__ W1,
    const float* __restrict__ eps, float* __restrict__ out)
{
    extern __shared__ char smem[];
    char*  Ap = smem + 65536;                            // [16 r][512 k] bf16
    float* Cl = (float*)smem;                            // [256 lc][20] (alias B0)

    const int t = threadIdx.x;
    const int w = t >> 6, lane = t & 63;
    const int lane15 = lane & 15, quad = lane >> 4;
    const int ax7 = lane15 & 7;
    const int half = blockIdx.x & 1;
    const int bm   = (blockIdx.x >> 1) * 16;
    const int hoff8 = half * 1024;                       // 16B-chunk col offset

    const char* wbase = (const char*)wcbt;

    // ---- issue B chunk 0 staging (4 x 16B per thread, identity copy)
    #pragma unroll
    for (int i = 0; i < 4; ++i) {
        int j = i * 512 + t;                             // local chunk 0..2047
        int src = hoff8 + j + (j & 1024);                // s-part cols +128
        gl_lds16(wbase + src * 16, smem + j * 16);
    }

    // ---- A panel staging: thread -> (row t>>5, k-range (t&31)*16..+16)
    {
        const int r = t >> 5, seg = t & 31;
        const float* xrow = x + (bm + r) * D_P1 + seg * 16;
        #pragma unroll
        for (int c2 = 0; c2 < 2; ++c2) {
            int g  = seg * 2 + c2;
            int cs = (g & ~7) | ((g & 7) ^ (r & 7));
            short8 pk;
            #pragma unroll
            for (int j = 0; j < 8; ++j) pk[j] = (short)bf16b(xrow[c2 * 8 + j]);
            *(short8*)(Ap + r * 1024 + cs * 16) = pk;
        }
    }

    // ---- early independent loads (k=512 fixup, eps, wl)
    const float e = eps[lane];
    float xl[4];
    #pragma unroll
    for (int i = 0; i < 4; ++i)
        xl[i] = x[(bm + quad * 4 + i) * D_P1 + 512];
    int   lc[2];  float wl[2];
    #pragma unroll
    for (int s = 0; s < 2; ++s) {
        lc[s] = w * 32 + s * 16 + lane15;
        int gc = half * 128 + lc[s] + (lc[s] & 128);     // global col
        wl[s] = (gc < 256) ? params[131072 + gc]
                           : sqrtf(fmaxf(params[LEN_M + 131072 + (gc - 256)], 0.0f) + 1e-6f);
    }
    const int cb0 = lc[0] * 128, cb1 = lc[1] * 128;

    floatx4 acc0 = {0.f,0.f,0.f,0.f}, acc1 = acc0;

    __syncthreads();                                     // A + B chunk 0 ready

    for (int kc = 0; kc < 8; ++kc) {
        if (kc < 7) {                                    // prefetch next chunk
            char* nbuf = smem + ((kc + 1) & 1) * 32768;
            #pragma unroll
            for (int i = 0; i < 4; ++i) {
                int j = i * 512 + t;
                int src = (kc + 1) * 4096 + hoff8 + j + (j & 1024);
                gl_lds16(wbase + src * 16, nbuf + j * 16);
            }
        }
        const char* Bb = smem + (kc & 1) * 32768;
        const char* Ab = Ap + lane15 * 1024 + kc * 128;
        #pragma unroll
        for (int kk = 0; kk < 2; ++kk) {
            const int off = ((kk * 4 + quad) ^ ax7) * 16;
            short8 a  = *(const short8*)(Ab + off);
            short8 b0 = *(const short8*)(Bb + cb0 + off);
            short8 b1 = *(const short8*)(Bb + cb1 + off);
            acc0 = __builtin_amdgcn_mfma_f32_16x16x32_bf16(a, b0, acc0, 0, 0, 0);
            acc1 = __builtin_amdgcn_mfma_f32_16x16x32_bf16(a, b1, acc1, 0, 0, 0);
        }
        __syncthreads();                                 // prefetch drained
    }

    // ---- fixup k=512 + C -> LDS [lc][20] (aliases B0; all B reads done)
    {
        floatx4 accs[2] = {acc0, acc1};
        #pragma unroll
        for (int s = 0; s < 2; ++s) {
            float4 o;
            o.x = accs[s][0] + xl[0] * wl[s];
            o.y = accs[s][1] + xl[1] * wl[s];
            o.z = accs[s][2] + xl[2] * wl[s];
            o.w = accs[s][3] + xl[3] * wl[s];
            *(float4*)&Cl[lc[s] * 20 + quad * 4] = o;
        }
    }
    __syncthreads();

    // ---- pred epilogue: lane = m; wave w rows rq..rq+1; 128 local h's
    const int rq = w * 2;
    v2f accp = {0.f, 0.f};
    const v2f e2 = {e, e}, z2 = {0.f, 0.f};

    #pragma unroll 8
    for (int hh = 0; hh < 128; ++hh) {
        const float w1h = W1[1 + half * 128 + hh];
        const v2f w2 = {w1h, w1h};
        const v2f av = *(const v2f*)&Cl[hh * 20 + rq];          // m-part (2 rows)
        const v2f bv = *(const v2f*)&Cl[(128 + hh) * 20 + rq];  // s-part
        v2f tt = __builtin_elementwise_max(__builtin_elementwise_fma(e2, bv, av), z2);
        accp = __builtin_elementwise_fma(tt, w2, accp);
    }
    if (half == 0) {
        const float b0 = W1[0];
        accp.x += b0; accp.y += b0;
    }

    float* op = out + (bm + rq) * 64 + lane;
    unsafeAtomicAdd(op,      accp.x);
    unsafeAtomicAdd(op + 64, accp.y);
}

// -------------------------------------------------------------- launch ------
extern "C" void kernel_launch(void* const* d_in, const int* in_sizes, int n_in,
                              void* d_out, int out_size, void* d_ws, size_t ws_size,
                              hipStream_t stream)
{
    const float* params = (const float*)d_in[0];
    const float* W1     = (const float*)d_in[1];
    const float* x      = (const float*)d_in[2];
    const float* eps    = (const float*)d_in[3];
    float* out = (float*)d_out;
    __hip_bfloat16* wcbt = (__hip_bfloat16*)d_ws;

    static bool attr_set = false;
    if (!attr_set) {
        hipFuncSetAttribute((const void*)main_kernel,
                            hipFuncAttributeMaxDynamicSharedMemorySize, 81920);
        attr_set = true;
    }

    prep_kernel<<<833, 256, 0, stream>>>(params, out, wcbt);
    main_kernel<<<512, 512, 81920, stream>>>(wcbt, params, x, W1, eps, out);
}

// Round 12
// 81.833 us; speedup vs baseline: 1.2053x; 1.0329x over previous
//
#include <hip/hip_runtime.h>
#include <hip/hip_bf16.h>
#include <math.h>

#define LEN_M   131328
#define D_P1    513
#define NROW    4096
#define PRED_ELEMS (NROW * 64)            // 262144

// ws: wcbt bf16, 512 KB: 8 k-chunks (kc) of 64 KB; each holds all 512 cols x
// 64 k as 16B chunks, swizzled: chunk_idx(c, g, kc) = kc*4096 + c*8 + (g^(c&7))
typedef __attribute__((ext_vector_type(8))) short short8;     // 8 bf16 = 4 VGPR
typedef __attribute__((ext_vector_type(4))) float floatx4;    // mfma acc
typedef __attribute__((ext_vector_type(2))) float v2f;        // packed fp32

__device__ __forceinline__ void gl_lds16(const void* g, void* l)
{
    __builtin_amdgcn_global_load_lds(
        (const __attribute__((address_space(1))) unsigned int*)g,
        (__attribute__((address_space(3))) unsigned int*)l, 16, 0, 0);
}

__device__ __forceinline__ unsigned short bf16b(float f)
{
    __hip_bfloat16 h = __float2bfloat16(f);
    return *(unsigned short*)&h;
}

// ------------------------------------------------------------------ prep ----
// blocks [0,513): m_w0 / v_w0 outputs (513*256 == LEN_M exactly)
// blocks [513,769): zero pred region (atomic accumulation base)
// blocks [769,833): build swizzled wcbt via LDS transpose
__global__ __launch_bounds__(256) void prep_kernel(
    const float* __restrict__ params, float* __restrict__ out,
    __hip_bfloat16* __restrict__ wcbt)
{
    __shared__ unsigned short T[64][65];
    const int bid = blockIdx.x;
    const int t   = threadIdx.x;

    if (bid < 513) {
        int i = bid * 256 + t;
        float m = params[i];
        float v = fmaxf(params[LEN_M + i], 0.0f) + 1e-6f;
        out[PRED_ELEMS + i]         = m;                 // m_w0
        out[PRED_ELEMS + LEN_M + i] = v;                 // v_w0
        return;
    }
    if (bid < 769) {
        int i = (bid - 513) * 1024 + t * 4;
        float4 z = {0.f, 0.f, 0.f, 0.f};
        *(float4*)(out + i) = z;
        return;
    }

    const int b2 = bid - 769;
    const int k0 = (b2 & 7) * 64;
    const int c0 = (b2 >> 3) * 64;
    const int hh = t & 63, kb = t >> 6;
    const bool spart = (c0 >= 256);
    const int hbase = c0 & 255;
    const float* src = params + (spart ? LEN_M : 0);

    #pragma unroll 4
    for (int p = 0; p < 16; ++p) {
        int kk = p * 4 + kb;
        float v = src[(k0 + kk) * 256 + hbase + hh];
        if (spart) v = sqrtf(fmaxf(v, 0.0f) + 1e-6f);
        T[kk][hh] = bf16b(v);
    }
    __syncthreads();

    const int cc = t >> 2, kq = t & 3;
    short8 lo, hi;
    #pragma unroll
    for (int j = 0; j < 8; ++j) lo[j] = (short)T[kq * 16 + j][cc];
    #pragma unroll
    for (int j = 0; j < 8; ++j) hi[j] = (short)T[kq * 16 + 8 + j][cc];

    const int cR = c0 + cc;
    const int g1 = (k0 >> 3) + 2 * kq;                   // global 16B-chunk 0..63
    const int g2 = g1 + 1;
    const int d1 = (g1 >> 3) * 4096 + cR * 8 + ((g1 & 7) ^ (cR & 7));
    const int d2 = (g2 >> 3) * 4096 + cR * 8 + ((g2 & 7) ^ (cR & 7));
    short* wb = (short*)wcbt;
    *(short8*)(wb + d1 * 8) = lo;
    *(short8*)(wb + d2 * 8) = hi;
}

// ------------------------------------------------------------------ main ----
// 512 blocks x 512 threads. Block (r = bid>>2, q = bid&3) owns rows
// [r*32, +32) x 128 cols: m-cols h in [q*64,+64) AND matching s-cols.
// B streamed in 8 chunks of [128 c][64 k] (16 KB) double-buffered from the
// pre-swizzled wcbt (IDENTITY copy — swizzle preserved; R11 bug was an extra
// XOR here); A panel 32x512 staged once. LDS = 2*16K + 32K = 64 KB ->
// 2 blocks/CU. Pred partials combined across col-quarters via unsafeAtomicAdd.
__global__ __launch_bounds__(512) void main_kernel(
    const __hip_bfloat16* __restrict__ wcbt, const float* __restrict__ params,
    const float* __restrict__ x, const float* __restrict__ W1,
    const float* __restrict__ eps, float* __restrict__ out)
{
    extern __shared__ char smem[];
    char*  Ap = smem + 32768;                            // [32 r][512 k] bf16
    float* Cl = (float*)smem;                            // [128 lc][36] (alias B)

    const int t = threadIdx.x;
    const int w = t >> 6, lane = t & 63;
    const int lane15 = lane & 15, quad = lane >> 4;
    const int ax7 = lane15 & 7;
    const int q  = blockIdx.x & 3;                       // col quarter
    const int bm = (blockIdx.x >> 2) * 32;               // row base

    const char* wbase = (const char*)wcbt;

    // ---- B staging mapping: local chunk j in [0,1024): lc=j>>3, g=j&7.
    //      IDENTITY within the column (swizzle stays baked in):
    //      src = cglob*8 + g,  cglob = q*64 + (lc&63) + (lc>=64)*256
    int bsrc_c0, bsrc_c1;
    {
        int j0 = t, j1 = 512 + t;
        int lc0 = j0 >> 3, g0 = j0 & 7;
        int lc1 = j1 >> 3, g1 = j1 & 7;
        int cg0 = q * 64 + (lc0 & 63) + ((lc0 >> 6) * 256);
        int cg1 = q * 64 + (lc1 & 63) + ((lc1 >> 6) * 256);
        bsrc_c0 = cg0 * 8 + g0;
        bsrc_c1 = cg1 * 8 + g1;
    }

    // ---- issue B chunk 0 staging (2 x 16B per thread, identity copy)
    gl_lds16(wbase + bsrc_c0 * 16, smem + t * 16);
    gl_lds16(wbase + bsrc_c1 * 16, smem + (512 + t) * 16);

    // ---- A panel staging: thread -> row t>>4, segs (t&15) and (t&15)+16
    {
        const int r = t >> 4, seg0 = t & 15;
        const float* xrow = x + (bm + r) * D_P1;
        #pragma unroll
        for (int ss = 0; ss < 2; ++ss) {
            const int seg = seg0 + ss * 16;
            #pragma unroll
            for (int c2 = 0; c2 < 2; ++c2) {
                int g  = seg * 2 + c2;
                int cs = (g & ~7) | ((g & 7) ^ (r & 7));
                short8 pk;
                #pragma unroll
                for (int j = 0; j < 8; ++j)
                    pk[j] = (short)bf16b(xrow[seg * 16 + c2 * 8 + j]);
                *(short8*)(Ap + r * 1024 + cs * 16) = pk;
            }
        }
    }

    // ---- early independent loads (k=512 fixup, eps, wl)
    const float e = eps[lane];
    const int rh = w & 1;                                // row half (16 rows)
    const int ct = w >> 1;                               // col tile 0..3
    float xl[4];
    #pragma unroll
    for (int i = 0; i < 4; ++i)
        xl[i] = x[(bm + rh * 16 + quad * 4 + i) * D_P1 + 512];
    const int gc0 = q * 64 + ct * 16 + lane15;           // m col
    const float wl0 = params[131072 + gc0];
    const float wl1 = sqrtf(fmaxf(params[LEN_M + 131072 + gc0], 0.0f) + 1e-6f);

    const int cb0 = (ct * 16 + lane15) * 128;            // B frag byte bases
    const int cb1 = cb0 + 64 * 128;
    const char* Abase = Ap + (rh * 16 + lane15) * 1024;

    floatx4 acc0 = {0.f,0.f,0.f,0.f}, acc1 = acc0;

    __syncthreads();                                     // A + B chunk 0 ready

    for (int kc = 0; kc < 8; ++kc) {
        if (kc < 7) {                                    // prefetch next chunk
            char* nbuf = smem + ((kc + 1) & 1) * 16384;
            const char* src = wbase + (kc + 1) * 65536;
            gl_lds16(src + bsrc_c0 * 16, nbuf + t * 16);
            gl_lds16(src + bsrc_c1 * 16, nbuf + (512 + t) * 16);
        }
        const char* Bb = smem + (kc & 1) * 16384;
        const char* Ab = Abase + kc * 128;
        #pragma unroll
        for (int kk = 0; kk < 2; ++kk) {
            const int off = ((kk * 4 + quad) ^ ax7) * 16;
            short8 a  = *(const short8*)(Ab + off);
            short8 b0 = *(const short8*)(Bb + cb0 + off);
            short8 b1 = *(const short8*)(Bb + cb1 + off);
            acc0 = __builtin_amdgcn_mfma_f32_16x16x32_bf16(a, b0, acc0, 0, 0, 0);
            acc1 = __builtin_amdgcn_mfma_f32_16x16x32_bf16(a, b1, acc1, 0, 0, 0);
        }
        __syncthreads();                                 // prefetch drained
    }

    // ---- fixup k=512 + C -> LDS [lc][36] (aliases B; all B reads done)
    {
        const int r0 = rh * 16 + quad * 4;
        float4 o0, o1;
        o0.x = acc0[0] + xl[0] * wl0;  o1.x = acc1[0] + xl[0] * wl1;
        o0.y = acc0[1] + xl[1] * wl0;  o1.y = acc1[1] + xl[1] * wl1;
        o0.z = acc0[2] + xl[2] * wl0;  o1.z = acc1[2] + xl[2] * wl1;
        o0.w = acc0[3] + xl[3] * wl0;  o1.w = acc1[3] + xl[3] * wl1;
        *(float4*)&Cl[(ct * 16 + lane15) * 36 + r0]      = o0;
        *(float4*)&Cl[(64 + ct * 16 + lane15) * 36 + r0] = o1;
    }
    __syncthreads();

    // ---- pred epilogue: lane = m; wave w rows w*4..w*4+3; 64 local h's
    const int rw = w * 4;
    v2f accp0 = {0.f, 0.f}, accp1 = {0.f, 0.f};
    const v2f e2 = {e, e}, z2 = {0.f, 0.f};

    #pragma unroll 8
    for (int hh = 0; hh < 64; ++hh) {
        const float w1h = W1[1 + q * 64 + hh];
        const v2f w2 = {w1h, w1h};
        const float4 av = *(const float4*)&Cl[hh * 36 + rw];         // m-part
        const float4 bv = *(const float4*)&Cl[(64 + hh) * 36 + rw];  // s-part
        v2f a01 = {av.x, av.y}, a23 = {av.z, av.w};
        v2f b01 = {bv.x, bv.y}, b23 = {bv.z, bv.w};
        v2f t01 = __builtin_elementwise_max(__builtin_elementwise_fma(e2, b01, a01), z2);
        v2f t23 = __builtin_elementwise_max(__builtin_elementwise_fma(e2, b23, a23), z2);
        accp0 = __builtin_elementwise_fma(t01, w2, accp0);
        accp1 = __builtin_elementwise_fma(t23, w2, accp1);
    }
    if (q == 0) {
        const float b0 = W1[0];
        accp0.x += b0; accp0.y += b0; accp1.x += b0; accp1.y += b0;
    }

    float* op = out + (bm + rw) * 64 + lane;
    unsafeAtomicAdd(op,       accp0.x);
    unsafeAtomicAdd(op + 64,  accp0.y);
    unsafeAtomicAdd(op + 128, accp1.x);
    unsafeAtomicAdd(op + 192, accp1.y);
}

// -------------------------------------------------------------- launch ------
extern "C" void kernel_launch(void* const* d_in, const int* in_sizes, int n_in,
                              void* d_out, int out_size, void* d_ws, size_t ws_size,
                              hipStream_t stream)
{
    const float* params = (const float*)d_in[0];
    const float* W1     = (const float*)d_in[1];
    const float* x      = (const float*)d_in[2];
    const float* eps    = (const float*)d_in[3];
    float* out = (float*)d_out;
    __hip_bfloat16* wcbt = (__hip_bfloat16*)d_ws;

    static bool attr_set = false;
    if (!attr_set) {
        hipFuncSetAttribute((const void*)main_kernel,
                            hipFuncAttributeMaxDynamicSharedMemorySize, 65536);
        attr_set = true;
    }

    prep_kernel<<<833, 256, 0, stream>>>(params, out, wcbt);
    main_kernel<<<512, 512, 65536, stream>>>(wcbt, params, x, W1, eps, out);
}